// Round 12
// baseline (57.653 us; speedup 1.0000x reference)
//
#include <hip/hip_runtime.h>

#define B_ 4
#define N_ 2048
#define IND_ 128
#define H_ 4
#define D_ 64
#define HD_ 256
#define LEAKY 0.2f
#define BNEPS 1e-5f
#define LOG2E 1.44269504088896340736f

typedef float f32x4 __attribute__((ext_vector_type(4)));
typedef float f32x16 __attribute__((ext_vector_type(16)));
typedef short s16x8 __attribute__((ext_vector_type(8)));
typedef unsigned int u32x4 __attribute__((ext_vector_type(4)));

static __device__ __forceinline__ unsigned short f2bf(float f) {
  unsigned u = __builtin_bit_cast(unsigned, f);
  u = (u + 0x7fffu + ((u >> 16) & 1u)) >> 16;   // RNE
  return (unsigned short)u;
}

// ------- Kernel A (fused): [gemm blocks 0..511] || [pack blocks 512..] ----
__global__ __launch_bounds__(256) void k_pre(const int* __restrict__ adj,
                                             const float* __restrict__ W,
                                             const float* __restrict__ h,
                                             const float* __restrict__ a,
                                             unsigned* __restrict__ bits,
                                             float* __restrict__ zbuf,
                                             unsigned short* __restrict__ wht,
                                             float* __restrict__ src,
                                             float* __restrict__ dst) {
  int t = threadIdx.x;
  if (blockIdx.x >= 512) {          // ---- pack role
    int pidx = blockIdx.x - 512;
    if (pidx == 0) {
      for (int i = t; i < 512; i += 256) zbuf[i] = 0.f;   // chsum|chsq
    }
    int idx = pidx * 256 + t;       // flat over N*N (row-major)
    int val = adj[idx] != 0;
    unsigned long long mm = __ballot(val);
    int lane = t & 63;
    if (lane == 0)       bits[idx >> 5] = (unsigned)mm;
    else if (lane == 32) bits[idx >> 5] = (unsigned)(mm >> 32);
    return;
  }
  // ---- gemm role: 512 blocks x 16 rows(n); wave w owns head w's 64 ch
  int w = t >> 6, lane = t & 63, m = lane & 15, g = lane >> 4;
  int r0 = blockIdx.x * 16;                    // flat row base in [0, B*N)
  int b = r0 >> 11, n0 = r0 & 2047;
  int hh = w;

  s16x8 Af[4][4];
#pragma unroll
  for (int chf = 0; chf < 4; chf++) {
    int chl = w * 64 + chf * 16 + m;
#pragma unroll
    for (int ks = 0; ks < 4; ks++) {
      int k0 = ks * 32 + g * 8;
      u32x4 au;
#pragma unroll
      for (int e2 = 0; e2 < 4; e2++) {
        float lo = W[(size_t)(k0 + 2 * e2) * 256 + chl];
        float hi = W[(size_t)(k0 + 2 * e2 + 1) * 256 + chl];
        unsigned rr_;
        asm("v_cvt_pk_bf16_f32 %0, %1, %2" : "=v"(rr_) : "v"(lo), "v"(hi));
        au[e2] = rr_;
      }
      Af[chf][ks] = __builtin_bit_cast(s16x8, au);
    }
  }
  s16x8 Bf[4];
#pragma unroll
  for (int ks = 0; ks < 4; ks++) {
    const float* hp = h + (size_t)(r0 + m) * 128 + ks * 32 + g * 8;
    f32x4 h0 = *(const f32x4*)hp;
    f32x4 h1 = *(const f32x4*)(hp + 4);
    u32x4 bu;
#pragma unroll
    for (int e = 0; e < 4; e++) {
      float lo = (e < 2) ? h0[2 * e] : h1[2 * e - 4];
      float hi = (e < 2) ? h0[2 * e + 1] : h1[2 * e - 3];
      unsigned rr_;
      asm("v_cvt_pk_bf16_f32 %0, %1, %2" : "=v"(rr_) : "v"(lo), "v"(hi));
      bu[e] = rr_;
    }
    Bf[ks] = __builtin_bit_cast(s16x8, bu);
  }

  f32x4 acc[4];
#pragma unroll
  for (int chf = 0; chf < 4; chf++) acc[chf] = (f32x4){0.f, 0.f, 0.f, 0.f};
#pragma unroll
  for (int ks = 0; ks < 4; ks++)
#pragma unroll
    for (int chf = 0; chf < 4; chf++)
      acc[chf] = __builtin_amdgcn_mfma_f32_16x16x32_bf16(Af[chf][ks], Bf[ks], acc[chf], 0, 0, 0);

  size_t obase = ((size_t)((b * 4 + hh) * 64)) * 2048 + n0 + m;
#pragma unroll
  for (int chf = 0; chf < 4; chf++) {
    int d = chf * 16 + g * 4;
#pragma unroll
    for (int reg = 0; reg < 4; reg++)
      wht[obase + (size_t)(d + reg) * 2048] = f2bf(acc[chf][reg]);
  }

  float sv = 0.f, dv = 0.f;
#pragma unroll
  for (int chf = 0; chf < 4; chf++)
#pragma unroll
    for (int reg = 0; reg < 4; reg++) {
      int d = chf * 16 + g * 4 + reg;
      float whv = acc[chf][reg];
      sv = fmaf(whv, a[hh * 128 + d] * LOG2E, sv);
      dv = fmaf(whv, a[hh * 128 + 64 + d] * LOG2E, dv);
    }
  sv += __shfl_xor(sv, 16); sv += __shfl_xor(sv, 32);
  dv += __shfl_xor(dv, 16); dv += __shfl_xor(dv, 32);
  if (g == 0) {
    src[(size_t)(b * 4 + hh) * 2048 + n0 + m] = sv;
    dst[(size_t)(b * 4 + hh) * 2048 + n0 + m] = dv;
  }
}

// ---------------- Kernel C: flash attention, async-staged 32x32 MFMA ------
// 256 thr / 4 waves: wave (iq,jq) = i-half(32 rows) x j-half(32 of 64-j tile).
// Wh tiles staged via global_load_lds into a 4-slot ring (linear dest,
// pre-swizzled global source); counted vmcnt(6) before each barrier -- loads
// stay in flight across barriers (T3+T4). Scores factorized
// p = max(Af_i*u_j, Bf_i*v_j); denominator via ones-B MFMA.
__global__ __launch_bounds__(256) void k_attn(const unsigned* __restrict__ adjb,
                                              const unsigned short* __restrict__ wht,
                                              const float* __restrict__ src,
                                              const float* __restrict__ dst,
                                              float* __restrict__ hnew,
                                              float* __restrict__ chsum,
                                              float* __restrict__ chsq) {
  __shared__ char ring[4 * 8192];         // 32KB: tile ring [slot][row64][128B]
  __shared__ float ul[2048], vl[2048];    // 16KB: u = 2^dstL, v = 2^(.2 dstL)
  __shared__ float redS[128], redQ[128];

  int t = threadIdx.x;
  int bid = blockIdx.x;
  int bh = bid & 15, it = bid >> 4;       // 16 consecutive blocks share adj rows
  int b = bh >> 2, hh = bh & 3;
  int i0 = it * 64;
  int q = t >> 6, lane = t & 63;
  int l31 = lane & 31, l5 = lane >> 5;
  int iq = q >> 1, jq = q & 1;

  {   // u/v tables for all 2048 j
    const f32x4* dg = (const f32x4*)(dst + (size_t)bh * 2048);
    f32x4 d0 = dg[2 * t], d1 = dg[2 * t + 1];
    f32x4 u0, u1, v0, v1;
#pragma unroll
    for (int e = 0; e < 4; e++) {
      u0[e] = __builtin_amdgcn_exp2f(d0[e]);
      v0[e] = __builtin_amdgcn_exp2f(0.2f * d0[e]);
      u1[e] = __builtin_amdgcn_exp2f(d1[e]);
      v1[e] = __builtin_amdgcn_exp2f(0.2f * d1[e]);
    }
    ((f32x4*)ul)[2 * t] = u0;  ((f32x4*)ul)[2 * t + 1] = u1;
    ((f32x4*)vl)[2 * t] = v0;  ((f32x4*)vl)[2 * t + 1] = v1;
  }

  int row_i = i0 + iq * 32 + l31;         // A-frag row this lane fills
  float srcL = src[(size_t)bh * 2048 + row_i];
  float Afc = __builtin_amdgcn_exp2f(srcL);
  float Bfc = __builtin_amdgcn_exp2f(LEAKY * srcL);

  s16x8 bones;
#pragma unroll
  for (int e = 0; e < 8; e++) bones[e] = (short)0x3F80;    // bf16 1.0

  f32x16 acc0, acc1, accd;
#pragma unroll
  for (int i = 0; i < 16; i++) { acc0[i] = 0.f; acc1[i] = 0.f; accd[i] = 0.f; }

  // ---- async staging: lane covers tile byte lane*16 (+ q*2048, s*1024).
  // LDS linear; global source pre-swizzled: row r = q*16 + s*8 + (lane>>3),
  // src col-slot c' = (lane&7) ^ ((lane>>3)&7).
  int rg = q * 16 + (lane >> 3);
  int csw = ((lane & 7) ^ ((lane >> 3) & 7)) << 4;
  const char* gsrc0 = (const char*)wht + (size_t)(bh * 64 + rg) * 4096 + csw;
  const char* gsrc1 = gsrc0 + 8 * 4096;
  char* ldst0 = ring + q * 2048;
  char* ldst1 = ldst0 + 1024;

#define GLD(gp_, lp_) __builtin_amdgcn_global_load_lds( \
    (const __attribute__((address_space(1))) void*)(gp_), \
    (__attribute__((address_space(3))) void*)(lp_), 16, 0, 0)
#define GLOADT(jt_) do { int sl_ = (jt_) & 3; \
    GLD(gsrc0 + (jt_) * 128, ldst0 + sl_ * 8192); \
    GLD(gsrc1 + (jt_) * 128, ldst1 + sl_ * 8192); } while (0)

  const unsigned* adjp = adjb + (size_t)row_i * 64 + jq;

  // loop-invariant read offsets (swizzled): chunk c col-slots
  int xsw = (l31 & 7) << 4;
  int xc0 = (jq * 64 + l5 * 16) ^ xsw;
  int xc1 = (jq * 64 + 32 + l5 * 16) ^ xsw;
  int dbase0 = l31 * 128;                 // dhalf 0 row base
  int dbase1 = (32 + l31) * 128;          // dhalf 1
  int uvbase = jq * 32 + l5 * 8;

  // prologue: adj 0..2, tiles 0..2, full drain once
  unsigned aw0 = adjp[0], aw1 = adjp[2], aw2 = adjp[4], awN = 0;
  GLOADT(0); GLOADT(1); GLOADT(2);
  __syncthreads();

  for (int jt = 0; jt < 32; jt++) {
    if (jt >= 1) {
      if (jt <= 29)      asm volatile("s_waitcnt vmcnt(6)" ::: "memory");
      else if (jt == 30) asm volatile("s_waitcnt vmcnt(3)" ::: "memory");
      else               asm volatile("s_waitcnt vmcnt(0)" ::: "memory");
      __builtin_amdgcn_s_barrier();
    }
    if (jt <= 28) { awN = adjp[2 * (jt + 3)]; GLOADT(jt + 3); }

    const char* rb = ring + (jt & 3) * 8192;
    const float* uj = ul + jt * 64 + uvbase;
    const float* vj = vl + jt * 64 + uvbase;
#pragma unroll
    for (int c = 0; c < 2; c++) {
      unsigned bitsv = (aw0 >> (c * 16 + l5 * 8)) & 0xffu;
      f32x4 u0 = *(const f32x4*)(uj + c * 16);
      f32x4 u1 = *(const f32x4*)(uj + c * 16 + 4);
      f32x4 v0 = *(const f32x4*)(vj + c * 16);
      f32x4 v1 = *(const f32x4*)(vj + c * 16 + 4);
      float pm[8];
#pragma unroll
      for (int e = 0; e < 8; e++) {
        float ue = (e < 4) ? u0[e] : u1[e - 4];
        float ve = (e < 4) ? v0[e] : v1[e - 4];
        float p = fmaxf(Afc * ue, Bfc * ve);
        unsigned keep = (unsigned)(((int)(bitsv << (31 - e))) >> 31);
        pm[e] = __builtin_bit_cast(float, __builtin_bit_cast(unsigned, p) & keep);
      }
      u32x4 afu;
#pragma unroll
      for (int e2 = 0; e2 < 4; e2++) {
        unsigned rr_;
        asm("v_cvt_pk_bf16_f32 %0, %1, %2" : "=v"(rr_) : "v"(pm[2 * e2]), "v"(pm[2 * e2 + 1]));
        afu[e2] = rr_;
      }
      s16x8 af = __builtin_bit_cast(s16x8, afu);
      int xc = c ? xc1 : xc0;
      s16x8 bf0 = *(const s16x8*)(rb + dbase0 + xc);
      s16x8 bf1 = *(const s16x8*)(rb + dbase1 + xc);
      acc0 = __builtin_amdgcn_mfma_f32_32x32x16_bf16(af, bf0, acc0, 0, 0, 0);
      acc1 = __builtin_amdgcn_mfma_f32_32x32x16_bf16(af, bf1, acc1, 0, 0, 0);
      accd = __builtin_amdgcn_mfma_f32_32x32x16_bf16(af, bones, accd, 0, 0, 0);
    }
    aw0 = aw1; aw1 = aw2; aw2 = awN;
  }
#undef GLOADT
#undef GLD

  // ---- combine jq halves through LDS (ring dead) -------------------------
  __syncthreads();
  float* bi = (float*)ring + iq * (32 * 66);   // [32 rows][66] (col 64 = den)
  if (jq == 1) {
#pragma unroll
    for (int reg = 0; reg < 16; reg++) {
      int cr = (reg & 3) + 8 * (reg >> 2) + 4 * l5;
      bi[cr * 66 + l31] = acc0[reg];
      bi[cr * 66 + 32 + l31] = acc1[reg];
      if (l31 == 0) bi[cr * 66 + 64] = accd[reg];
    }
  }
  __syncthreads();
  if (jq == 0) {
    float sums0 = 0.f, sums1 = 0.f, sqs0 = 0.f, sqs1 = 0.f;
#pragma unroll
    for (int reg = 0; reg < 16; reg++) {
      int cr = (reg & 3) + 8 * (reg >> 2) + 4 * l5;
      float a0 = acc0[reg] + bi[cr * 66 + l31];
      float a1 = acc1[reg] + bi[cr * 66 + 32 + l31];
      float dtot = accd[reg] + bi[cr * 66 + 64];
      float inv = dtot > 0.f ? 1.0f / dtot : 0.f;   // all-masked row -> zeros
      float o0 = a0 * inv, o1 = a1 * inv;
      int n = i0 + iq * 32 + cr;
      float* hp = hnew + ((size_t)(b * 2048 + n)) * 256 + hh * 64;
      hp[l31] = o0;
      hp[32 + l31] = o1;
      sums0 += o0; sums1 += o1;
      sqs0 += o0 * o0; sqs1 += o1 * o1;
    }
    sums0 += __shfl_xor(sums0, 32); sums1 += __shfl_xor(sums1, 32);
    sqs0 += __shfl_xor(sqs0, 32);   sqs1 += __shfl_xor(sqs1, 32);
    if (lane < 32) {
      redS[iq * 64 + l31] = sums0;  redS[iq * 64 + 32 + l31] = sums1;
      redQ[iq * 64 + l31] = sqs0;   redQ[iq * 64 + 32 + l31] = sqs1;
    }
  }
  __syncthreads();
  if (t < 64) {
    float ts2 = redS[t] + redS[64 + t];
    float tq = redQ[t] + redQ[64 + t];
    atomicAdd(&chsum[hh * 64 + t], ts2);
    atomicAdd(&chsq[hh * 64 + t], tq);
  }
}

// ---------------- Kernel D: BN(+stats inline) + ELU -----------------------
__global__ __launch_bounds__(256) void k_bn_elu(const float* __restrict__ hnew,
                                                const float* __restrict__ chsum,
                                                const float* __restrict__ chsq,
                                                const float* __restrict__ gamma,
                                                const float* __restrict__ beta,
                                                float* __restrict__ out) {
  int idx4 = blockIdx.x * 256 + threadIdx.x;
  f32x4 x = ((const f32x4*)hnew)[idx4];
  int c0 = (idx4 * 4) & 255;
  f32x4 s = *(const f32x4*)(chsum + c0);
  f32x4 sq = *(const f32x4*)(chsq + c0);
  f32x4 gm = *(const f32x4*)(gamma + c0);
  f32x4 bt = *(const f32x4*)(beta + c0);
  f32x4 y;
#pragma unroll
  for (int e = 0; e < 4; e++) {
    float mean = s[e] * (1.0f / 8192.0f);
    float var = sq[e] * (1.0f / 8192.0f) - mean * mean;
    float sc = gm[e] * rsqrtf(var + BNEPS);
    float v = (x[e] - mean) * sc + bt[e];
    y[e] = v > 0.f ? v : expm1f(v);
  }
  ((f32x4*)out)[idx4] = y;
}

extern "C" void kernel_launch(void* const* d_in, const int* in_sizes, int n_in,
                              void* d_out, int out_size, void* d_ws, size_t ws_size,
                              hipStream_t stream) {
  const float* h = (const float*)d_in[0];
  const float* W = (const float*)d_in[1];
  const float* a = (const float*)d_in[2];
  const float* gamma = (const float*)d_in[3];
  const float* beta = (const float*)d_in[4];
  const int* adj = (const int*)d_in[5];

  char* ws = (char*)d_ws;
  unsigned* adjb = (unsigned*)ws;                                  // 512 KB
  unsigned short* wht = (unsigned short*)(ws + (512 << 10));       // 4 MB
  float* src = (float*)(ws + (512 << 10) + (4 << 20));             // 128 KB
  float* dst = src + 16 * 2048;                                    // 128 KB
  float* chsum = dst + 16 * 2048;                                  // 256
  float* chsq = chsum + 256;                                       // 256
  float* hnew = (float*)(ws + (512 << 10) + (5 << 20));            // 8 MB

  k_pre<<<512 + (N_ * N_) / 256, 256, 0, stream>>>(adj, W, h, a, adjb, chsum,
                                                   wht, src, dst);
  k_attn<<<B_ * H_ * (N_ / 64), 256, 0, stream>>>(adjb, wht, src, dst,
                                                  hnew, chsum, chsq);
  k_bn_elu<<<(B_ * N_ * HD_) / 1024, 256, 0, stream>>>(hnew, chsum, chsq,
                                                       gamma, beta, (float*)d_out);
}

// Round 13
// 56.636 us; speedup vs baseline: 1.0180x; 1.0180x over previous
//
#include <hip/hip_runtime.h>

#define B_ 4
#define N_ 2048
#define IND_ 128
#define H_ 4
#define D_ 64
#define HD_ 256
#define LEAKY 0.2f
#define BNEPS 1e-5f
#define LOG2E 1.44269504088896340736f

typedef float f32x4 __attribute__((ext_vector_type(4)));
typedef short s16x8 __attribute__((ext_vector_type(8)));
typedef unsigned int u32x2 __attribute__((ext_vector_type(2)));
typedef unsigned int u32x4 __attribute__((ext_vector_type(4)));

static __device__ __forceinline__ unsigned short f2bf(float f) {
  unsigned u = __builtin_bit_cast(unsigned, f);
  u = (u + 0x7fffu + ((u >> 16) & 1u)) >> 16;   // RNE
  return (unsigned short)u;
}

// ------- Kernel A (fused): [gemm blocks 0..511] || [pack blocks 512..] ----
__global__ __launch_bounds__(256) void k_pre(const int* __restrict__ adj,
                                             const float* __restrict__ W,
                                             const float* __restrict__ h,
                                             const float* __restrict__ a,
                                             unsigned* __restrict__ bits,
                                             float* __restrict__ zbuf,
                                             unsigned short* __restrict__ wht,
                                             float* __restrict__ src,
                                             float* __restrict__ dst) {
  int t = threadIdx.x;
  if (blockIdx.x >= 512) {          // ---- pack role
    int pidx = blockIdx.x - 512;
    if (pidx == 0) {
      for (int i = t; i < 512; i += 256) zbuf[i] = 0.f;   // chsum|chsq
    }
    int idx = pidx * 256 + t;       // flat over N*N (row-major)
    int val = adj[idx] != 0;
    unsigned long long mm = __ballot(val);
    int lane = t & 63;
    if (lane == 0)       bits[idx >> 5] = (unsigned)mm;
    else if (lane == 32) bits[idx >> 5] = (unsigned)(mm >> 32);
    return;
  }
  // ---- gemm role: 512 blocks x 16 rows(n); wave w owns head w's 64 ch
  int w = t >> 6, lane = t & 63, m = lane & 15, g = lane >> 4;
  int r0 = blockIdx.x * 16;                    // flat row base in [0, B*N)
  int b = r0 >> 11, n0 = r0 & 2047;
  int hh = w;

  s16x8 Af[4][4];
#pragma unroll
  for (int chf = 0; chf < 4; chf++) {
    int chl = w * 64 + chf * 16 + m;
#pragma unroll
    for (int ks = 0; ks < 4; ks++) {
      int k0 = ks * 32 + g * 8;
      u32x4 au;
#pragma unroll
      for (int e2 = 0; e2 < 4; e2++) {
        float lo = W[(size_t)(k0 + 2 * e2) * 256 + chl];
        float hi = W[(size_t)(k0 + 2 * e2 + 1) * 256 + chl];
        unsigned rr_;
        asm("v_cvt_pk_bf16_f32 %0, %1, %2" : "=v"(rr_) : "v"(lo), "v"(hi));
        au[e2] = rr_;
      }
      Af[chf][ks] = __builtin_bit_cast(s16x8, au);
    }
  }
  s16x8 Bf[4];
#pragma unroll
  for (int ks = 0; ks < 4; ks++) {
    const float* hp = h + (size_t)(r0 + m) * 128 + ks * 32 + g * 8;
    f32x4 h0 = *(const f32x4*)hp;
    f32x4 h1 = *(const f32x4*)(hp + 4);
    u32x4 bu;
#pragma unroll
    for (int e = 0; e < 4; e++) {
      float lo = (e < 2) ? h0[2 * e] : h1[2 * e - 4];
      float hi = (e < 2) ? h0[2 * e + 1] : h1[2 * e - 3];
      unsigned rr_;
      asm("v_cvt_pk_bf16_f32 %0, %1, %2" : "=v"(rr_) : "v"(lo), "v"(hi));
      bu[e] = rr_;
    }
    Bf[ks] = __builtin_bit_cast(s16x8, bu);
  }

  f32x4 acc[4];
#pragma unroll
  for (int chf = 0; chf < 4; chf++) acc[chf] = (f32x4){0.f, 0.f, 0.f, 0.f};
#pragma unroll
  for (int ks = 0; ks < 4; ks++)
#pragma unroll
    for (int chf = 0; chf < 4; chf++)
      acc[chf] = __builtin_amdgcn_mfma_f32_16x16x32_bf16(Af[chf][ks], Bf[ks], acc[chf], 0, 0, 0);

  size_t obase = ((size_t)((b * 4 + hh) * 64)) * 2048 + n0 + m;
#pragma unroll
  for (int chf = 0; chf < 4; chf++) {
    int d = chf * 16 + g * 4;
#pragma unroll
    for (int reg = 0; reg < 4; reg++)
      wht[obase + (size_t)(d + reg) * 2048] = f2bf(acc[chf][reg]);
  }

  float sv = 0.f, dv = 0.f;
#pragma unroll
  for (int chf = 0; chf < 4; chf++)
#pragma unroll
    for (int reg = 0; reg < 4; reg++) {
      int d = chf * 16 + g * 4 + reg;
      float whv = acc[chf][reg];
      sv = fmaf(whv, a[hh * 128 + d] * LOG2E, sv);
      dv = fmaf(whv, a[hh * 128 + 64 + d] * LOG2E, dv);
    }
  sv += __shfl_xor(sv, 16); sv += __shfl_xor(sv, 32);
  dv += __shfl_xor(dv, 16); dv += __shfl_xor(dv, 32);
  if (g == 0) {
    src[(size_t)(b * 4 + hh) * 2048 + n0 + m] = sv;
    dst[(size_t)(b * 4 + hh) * 2048 + n0 + m] = dv;
  }
}

// ---------------- Kernel C: flash attention (r9 pipeline, LDS diet) -------
// 256 thr / 4 waves: wave (half, wv) = j-half x i-half; each wave carries
// TWO 16-row A-frags (32 rows) sharing B-frag and u/v reads. u/v packed as
// bf16 pairs (one u32/j): per-jt LDS reads 16 -> 12 b128 serving 2x rows.
// Factorized scores p = max(Af*u, Bf*v); den via ones-B MFMA.
__global__ __launch_bounds__(256) void k_attn(const unsigned* __restrict__ adjb,
                                              const unsigned short* __restrict__ wht,
                                              const float* __restrict__ src,
                                              const float* __restrict__ dst,
                                              float* __restrict__ hnew,
                                              float* __restrict__ chsum,
                                              float* __restrict__ chsq) {
  __shared__ u32x4 whb4[2048];            // 32KB: 2 halves x 2 dbuf x 8KB, swizzled
  __shared__ unsigned uvl[2048];          // 8KB: packed bf16(u) | bf16(v)<<16
  __shared__ float redS[128], redQ[128];

  int t = threadIdx.x;
  int bid = blockIdx.x;
  int bh = bid & 15, it = bid >> 4;       // 16 consecutive blocks share adj rows
  int b = bh >> 2, hh = bh & 3;
  int i0 = it * 64;
  int w8 = t >> 6, half = w8 >> 1, wv = w8 & 1;
  int lane = t & 63, m = lane & 15, g = lane >> 4;

  {   // packed u/v for all 2048 j (u = 2^dstL, v = 2^(.2 dstL))
    const f32x4* dg = (const f32x4*)(dst + (size_t)bh * 2048);
    f32x4 d0 = dg[2 * t], d1 = dg[2 * t + 1];
    u32x4 p0, p1;
#pragma unroll
    for (int e = 0; e < 4; e++) {
      float u0 = __builtin_amdgcn_exp2f(d0[e]);
      float v0 = __builtin_amdgcn_exp2f(0.2f * d0[e]);
      float u1 = __builtin_amdgcn_exp2f(d1[e]);
      float v1 = __builtin_amdgcn_exp2f(0.2f * d1[e]);
      unsigned r0_, r1_;
      asm("v_cvt_pk_bf16_f32 %0, %1, %2" : "=v"(r0_) : "v"(u0), "v"(v0));
      asm("v_cvt_pk_bf16_f32 %0, %1, %2" : "=v"(r1_) : "v"(u1), "v"(v1));
      p0[e] = r0_; p1[e] = r1_;
    }
    ((u32x4*)uvl)[2 * t] = p0;
    ((u32x4*)uvl)[2 * t + 1] = p1;
  }

  int ri0 = i0 + wv * 32 + m;             // frag0 row
  int ri1 = ri0 + 16;                     // frag1 row
  float s0 = src[(size_t)bh * 2048 + ri0];
  float s1 = src[(size_t)bh * 2048 + ri1];
  float Af0 = __builtin_amdgcn_exp2f(s0), Bf0 = __builtin_amdgcn_exp2f(LEAKY * s0);
  float Af1 = __builtin_amdgcn_exp2f(s1), Bf1 = __builtin_amdgcn_exp2f(LEAKY * s1);

  s16x8 bones;
#pragma unroll
  for (int e = 0; e < 8; e++) bones[e] = (short)0x3F80;    // bf16 1.0

  f32x4 acc0[4], acc1[4], accd0, accd1;
#pragma unroll
  for (int db = 0; db < 4; db++) {
    acc0[db] = (f32x4){0.f, 0.f, 0.f, 0.f};
    acc1[db] = (f32x4){0.f, 0.f, 0.f, 0.f};
  }
  accd0 = (f32x4){0.f, 0.f, 0.f, 0.f};
  accd1 = (f32x4){0.f, 0.f, 0.f, 0.f};

  // staging: 128 threads per half, 64B (4x16B) each
  char* wbase = (char*)whb4 + half * 16384;
  int ts = t & 127;
  int r_ = ts >> 1, c2 = ts & 1;
  int jtbase = half * 16;
  const char* gbase = (const char*)(wht + (size_t)(bh * 64 + r_) * 2048)
                      + jtbase * 128 + c2 * 64;
  int sw = (r_ & 7) << 4;
  u32x4 R0_, R1_, R2_, R3_;
  const u32x2* adjr0 = (const u32x2*)(adjb + (size_t)ri0 * 64 + jtbase * 2);
  const u32x2* adjr1 = (const u32x2*)(adjb + (size_t)ri1 * 64 + jtbase * 2);

#define LOADT(jt_) { const u32x4* gp = (const u32x4*)(gbase + (jt_) * 128); \
                     R0_ = gp[0]; R1_ = gp[1]; R2_ = gp[2]; R3_ = gp[3]; }
#define WRITET(pb_) { char* wb_ = (pb_) + r_ * 128; \
                      *(u32x4*)(wb_ + ((c2 * 64 +  0) ^ sw)) = R0_; \
                      *(u32x4*)(wb_ + ((c2 * 64 + 16) ^ sw)) = R1_; \
                      *(u32x4*)(wb_ + ((c2 * 64 + 32) ^ sw)) = R2_; \
                      *(u32x4*)(wb_ + ((c2 * 64 + 48) ^ sw)) = R3_; }

  LOADT(0); WRITET(wbase); LOADT(1);
  u32x2 a0c = adjr0[0], a1c = adjr1[0];

  for (int jt = 0; jt < 16; jt++) {
    int cur = jt & 1;
    __syncthreads();                      // drains prefetch vmem + dbuf writes
    if (jt < 15) WRITET(wbase + (cur ^ 1) * 8192);   // tile jt+1 -> other buf
    if (jt < 14) LOADT(jt + 2);                      // issue tile jt+2 loads
    u32x2 a0n, a1n;
    if (jt < 15) { a0n = adjr0[jt + 1]; a1n = adjr1[jt + 1]; }
    const char* wbufc = wbase + cur * 8192;
    int jglob = jtbase + jt;

#pragma unroll
    for (int ks = 0; ks < 2; ks++) {
      unsigned bits0 = (a0c[ks] >> (g * 8)) & 0xffu;
      unsigned bits1 = (a1c[ks] >> (g * 8)) & 0xffu;
      const u32x4* uvp = (const u32x4*)&uvl[jglob * 64 + ks * 32 + g * 8];
      u32x4 q0 = uvp[0], q1 = uvp[1];
      float pm0[8], pm1[8];
#pragma unroll
      for (int e = 0; e < 8; e++) {
        unsigned pk = (e < 4) ? q0[e] : q1[e - 4];
        float uf = __builtin_bit_cast(float, pk << 16);
        float vf = __builtin_bit_cast(float, pk & 0xffff0000u);
        float p0 = fmaxf(Af0 * uf, Bf0 * vf);
        float p1 = fmaxf(Af1 * uf, Bf1 * vf);
        unsigned k0 = (unsigned)(((int)(bits0 << (31 - e))) >> 31);
        unsigned k1 = (unsigned)(((int)(bits1 << (31 - e))) >> 31);
        pm0[e] = __builtin_bit_cast(float, __builtin_bit_cast(unsigned, p0) & k0);
        pm1[e] = __builtin_bit_cast(float, __builtin_bit_cast(unsigned, p1) & k1);
      }
      u32x4 af0u, af1u;
#pragma unroll
      for (int e2 = 0; e2 < 4; e2++) {
        unsigned r0_, r1_;
        asm("v_cvt_pk_bf16_f32 %0, %1, %2" : "=v"(r0_) : "v"(pm0[2 * e2]), "v"(pm0[2 * e2 + 1]));
        asm("v_cvt_pk_bf16_f32 %0, %1, %2" : "=v"(r1_) : "v"(pm1[2 * e2]), "v"(pm1[2 * e2 + 1]));
        af0u[e2] = r0_; af1u[e2] = r1_;
      }
      s16x8 af0 = __builtin_bit_cast(s16x8, af0u);
      s16x8 af1 = __builtin_bit_cast(s16x8, af1u);
#pragma unroll
      for (int db = 0; db < 4; db++) {
        int dl = db * 16 + m;
        int off = dl * 128 + ((ks * 64 + g * 16) ^ ((dl & 7) << 4));
        s16x8 bf = *(const s16x8*)(wbufc + off);
        acc0[db] = __builtin_amdgcn_mfma_f32_16x16x32_bf16(af0, bf, acc0[db], 0, 0, 0);
        acc1[db] = __builtin_amdgcn_mfma_f32_16x16x32_bf16(af1, bf, acc1[db], 0, 0, 0);
      }
      accd0 = __builtin_amdgcn_mfma_f32_16x16x32_bf16(af0, bones, accd0, 0, 0, 0);
      accd1 = __builtin_amdgcn_mfma_f32_16x16x32_bf16(af1, bones, accd1, 0, 0, 0);
    }
    a0c = a0n; a1c = a1n;
  }
#undef LOADT
#undef WRITET

  __syncthreads();                        // whb4 dead; reuse as combine buffer
  float* accl = (float*)whb4;             // [64 rows][65] (col 64 = den)
  if (half == 1) {
#pragma unroll
    for (int db = 0; db < 4; db++)
#pragma unroll
      for (int r = 0; r < 4; r++) {
        accl[(wv * 32 + 4 * g + r) * 65 + db * 16 + m] = acc0[db][r];
        accl[(wv * 32 + 16 + 4 * g + r) * 65 + db * 16 + m] = acc1[db][r];
      }
    if (m == 0) {
#pragma unroll
      for (int r = 0; r < 4; r++) {
        accl[(wv * 32 + 4 * g + r) * 65 + 64] = accd0[r];
        accl[(wv * 32 + 16 + 4 * g + r) * 65 + 64] = accd1[r];
      }
    }
  }
  __syncthreads();

  if (half == 0) {
    float sums[4] = {0.f, 0.f, 0.f, 0.f}, sqs[4] = {0.f, 0.f, 0.f, 0.f};
#pragma unroll
    for (int fr = 0; fr < 2; fr++) {
#pragma unroll
      for (int r = 0; r < 4; r++) {
        int rr = wv * 32 + fr * 16 + 4 * g + r;
        float dtot = (fr ? accd1[r] : accd0[r]) + accl[rr * 65 + 64];
        float inv = dtot > 0.f ? 1.0f / dtot : 0.f;   // all-masked -> zeros
        int n = i0 + rr;
#pragma unroll
        for (int db = 0; db < 4; db++) {
          float av = (fr ? acc1[db][r] : acc0[db][r]) + accl[rr * 65 + db * 16 + m];
          float val = av * inv;
          hnew[(size_t)(b * 2048 + n) * 256 + hh * 64 + db * 16 + m] = val;
          sums[db] += val;
          sqs[db] += val * val;
        }
      }
    }
#pragma unroll
    for (int db = 0; db < 4; db++) {
      sums[db] += __shfl_xor(sums[db], 16); sums[db] += __shfl_xor(sums[db], 32);
      sqs[db]  += __shfl_xor(sqs[db], 16);  sqs[db]  += __shfl_xor(sqs[db], 32);
    }
    if (g == 0) {
#pragma unroll
      for (int db = 0; db < 4; db++) {
        redS[wv * 64 + db * 16 + m] = sums[db];
        redQ[wv * 64 + db * 16 + m] = sqs[db];
      }
    }
  }
  __syncthreads();
  if (t < 64) {
    float ts2 = redS[t] + redS[64 + t];
    float tq = redQ[t] + redQ[64 + t];
    atomicAdd(&chsum[hh * 64 + t], ts2);
    atomicAdd(&chsq[hh * 64 + t], tq);
  }
}

// ---------------- Kernel D: BN(+stats inline) + ELU -----------------------
__global__ __launch_bounds__(256) void k_bn_elu(const float* __restrict__ hnew,
                                                const float* __restrict__ chsum,
                                                const float* __restrict__ chsq,
                                                const float* __restrict__ gamma,
                                                const float* __restrict__ beta,
                                                float* __restrict__ out) {
  int idx4 = blockIdx.x * 256 + threadIdx.x;
  f32x4 x = ((const f32x4*)hnew)[idx4];
  int c0 = (idx4 * 4) & 255;
  f32x4 s = *(const f32x4*)(chsum + c0);
  f32x4 sq = *(const f32x4*)(chsq + c0);
  f32x4 gm = *(const f32x4*)(gamma + c0);
  f32x4 bt = *(const f32x4*)(beta + c0);
  f32x4 y;
#pragma unroll
  for (int e = 0; e < 4; e++) {
    float mean = s[e] * (1.0f / 8192.0f);
    float var = sq[e] * (1.0f / 8192.0f) - mean * mean;
    float sc = gm[e] * rsqrtf(var + BNEPS);
    float v = (x[e] - mean) * sc + bt[e];
    y[e] = v > 0.f ? v : expm1f(v);
  }
  ((f32x4*)out)[idx4] = y;
}

extern "C" void kernel_launch(void* const* d_in, const int* in_sizes, int n_in,
                              void* d_out, int out_size, void* d_ws, size_t ws_size,
                              hipStream_t stream) {
  const float* h = (const float*)d_in[0];
  const float* W = (const float*)d_in[1];
  const float* a = (const float*)d_in[2];
  const float* gamma = (const float*)d_in[3];
  const float* beta = (const float*)d_in[4];
  const int* adj = (const int*)d_in[5];

  char* ws = (char*)d_ws;
  unsigned* adjb = (unsigned*)ws;                                  // 512 KB
  unsigned short* wht = (unsigned short*)(ws + (512 << 10));       // 4 MB
  float* src = (float*)(ws + (512 << 10) + (4 << 20));             // 128 KB
  float* dst = src + 16 * 2048;                                    // 128 KB
  float* chsum = dst + 16 * 2048;                                  // 256
  float* chsq = chsum + 256;                                       // 256
  float* hnew = (float*)(ws + (512 << 10) + (5 << 20));            // 8 MB

  k_pre<<<512 + (N_ * N_) / 256, 256, 0, stream>>>(adj, W, h, a, adjb, chsum,
                                                   wht, src, dst);
  k_attn<<<B_ * H_ * (N_ / 64), 256, 0, stream>>>(adjb, wht, src, dst,
                                                  hnew, chsum, chsq);
  k_bn_elu<<<(B_ * N_ * HD_) / 1024, 256, 0, stream>>>(hnew, chsum, chsq,
                                                       gamma, beta, (float*)d_out);
}

// Round 14
// 51.929 us; speedup vs baseline: 1.1102x; 1.0906x over previous
//
#include <hip/hip_runtime.h>

#define B_ 4
#define N_ 2048
#define IND_ 128
#define H_ 4
#define D_ 64
#define HD_ 256
#define LEAKY 0.2f
#define BNEPS 1e-5f
#define LOG2E 1.44269504088896340736f

typedef float f32x4 __attribute__((ext_vector_type(4)));
typedef short s16x8 __attribute__((ext_vector_type(8)));
typedef unsigned int u32x2 __attribute__((ext_vector_type(2)));
typedef unsigned int u32x4 __attribute__((ext_vector_type(4)));

static __device__ __forceinline__ unsigned short f2bf(float f) {
  unsigned u = __builtin_bit_cast(unsigned, f);
  u = (u + 0x7fffu + ((u >> 16) & 1u)) >> 16;   // RNE
  return (unsigned short)u;
}

// ------- Kernel A (fused): [gemm blocks 0..511] || [pack blocks 512..] ----
__global__ __launch_bounds__(256) void k_pre(const int* __restrict__ adj,
                                             const float* __restrict__ W,
                                             const float* __restrict__ h,
                                             const float* __restrict__ a,
                                             unsigned* __restrict__ bits,
                                             float* __restrict__ zbuf,
                                             unsigned short* __restrict__ wht,
                                             float* __restrict__ src,
                                             float* __restrict__ dst) {
  int t = threadIdx.x;
  if (blockIdx.x >= 512) {          // ---- pack role
    int pidx = blockIdx.x - 512;
    if (pidx == 0) {
      for (int i = t; i < 512; i += 256) zbuf[i] = 0.f;   // chsum|chsq
    }
    int idx = pidx * 256 + t;       // flat over N*N (row-major)
    int val = adj[idx] != 0;
    unsigned long long mm = __ballot(val);
    int lane = t & 63;
    if (lane == 0)       bits[idx >> 5] = (unsigned)mm;
    else if (lane == 32) bits[idx >> 5] = (unsigned)(mm >> 32);
    return;
  }
  // ---- gemm role: 512 blocks x 16 rows(n); wave w owns head w's 64 ch
  int w = t >> 6, lane = t & 63, m = lane & 15, g = lane >> 4;
  int r0 = blockIdx.x * 16;                    // flat row base in [0, B*N)
  int b = r0 >> 11, n0 = r0 & 2047;
  int hh = w;

  s16x8 Af[4][4];
#pragma unroll
  for (int chf = 0; chf < 4; chf++) {
    int chl = w * 64 + chf * 16 + m;
#pragma unroll
    for (int ks = 0; ks < 4; ks++) {
      int k0 = ks * 32 + g * 8;
      u32x4 au;
#pragma unroll
      for (int e2 = 0; e2 < 4; e2++) {
        float lo = W[(size_t)(k0 + 2 * e2) * 256 + chl];
        float hi = W[(size_t)(k0 + 2 * e2 + 1) * 256 + chl];
        unsigned rr_;
        asm("v_cvt_pk_bf16_f32 %0, %1, %2" : "=v"(rr_) : "v"(lo), "v"(hi));
        au[e2] = rr_;
      }
      Af[chf][ks] = __builtin_bit_cast(s16x8, au);
    }
  }
  s16x8 Bf[4];
#pragma unroll
  for (int ks = 0; ks < 4; ks++) {
    const float* hp = h + (size_t)(r0 + m) * 128 + ks * 32 + g * 8;
    f32x4 h0 = *(const f32x4*)hp;
    f32x4 h1 = *(const f32x4*)(hp + 4);
    u32x4 bu;
#pragma unroll
    for (int e = 0; e < 4; e++) {
      float lo = (e < 2) ? h0[2 * e] : h1[2 * e - 4];
      float hi = (e < 2) ? h0[2 * e + 1] : h1[2 * e - 3];
      unsigned rr_;
      asm("v_cvt_pk_bf16_f32 %0, %1, %2" : "=v"(rr_) : "v"(lo), "v"(hi));
      bu[e] = rr_;
    }
    Bf[ks] = __builtin_bit_cast(s16x8, bu);
  }

  f32x4 acc[4];
#pragma unroll
  for (int chf = 0; chf < 4; chf++) acc[chf] = (f32x4){0.f, 0.f, 0.f, 0.f};
#pragma unroll
  for (int ks = 0; ks < 4; ks++)
#pragma unroll
    for (int chf = 0; chf < 4; chf++)
      acc[chf] = __builtin_amdgcn_mfma_f32_16x16x32_bf16(Af[chf][ks], Bf[ks], acc[chf], 0, 0, 0);

  size_t obase = ((size_t)((b * 4 + hh) * 64)) * 2048 + n0 + m;
#pragma unroll
  for (int chf = 0; chf < 4; chf++) {
    int d = chf * 16 + g * 4;
#pragma unroll
    for (int reg = 0; reg < 4; reg++)
      wht[obase + (size_t)(d + reg) * 2048] = f2bf(acc[chf][reg]);
  }

  float sv = 0.f, dv = 0.f;
#pragma unroll
  for (int chf = 0; chf < 4; chf++)
#pragma unroll
    for (int reg = 0; reg < 4; reg++) {
      int d = chf * 16 + g * 4 + reg;
      float whv = acc[chf][reg];
      sv = fmaf(whv, a[hh * 128 + d] * LOG2E, sv);
      dv = fmaf(whv, a[hh * 128 + 64 + d] * LOG2E, dv);
    }
  sv += __shfl_xor(sv, 16); sv += __shfl_xor(sv, 32);
  dv += __shfl_xor(dv, 16); dv += __shfl_xor(dv, 32);
  if (g == 0) {
    src[(size_t)(b * 4 + hh) * 2048 + n0 + m] = sv;
    dst[(size_t)(b * 4 + hh) * 2048 + n0 + m] = dv;
  }
}

// ---------------- Kernel C: flash attention, j split across wave-halves ---
// EXACT r9 structure (512 thr, 8 waves, dbuf staging, LDS combine) with ONE
// change: u/v tables packed as bf16 pairs (one u32 per j) -> per-(jt,ks)
// LDS reads drop 8 -> 6 b128. Factorized scores p = max(Af*u, Bf*v);
// denominator via ones-B MFMA.
__global__ __launch_bounds__(512) void k_attn(const unsigned* __restrict__ adjb,
                                              const unsigned short* __restrict__ wht,
                                              const float* __restrict__ src,
                                              const float* __restrict__ dst,
                                              float* __restrict__ hnew,
                                              float* __restrict__ chsum,
                                              float* __restrict__ chsq) {
  __shared__ u32x4 whb4[2048];            // 2 halves x 2 dbuf x 8KB, XOR-swizzled
  __shared__ unsigned uvl[2048];          // 8KB: bf16(u) in lo16 | bf16(v) in hi16
  __shared__ float redS[256], redQ[256];

  int t = threadIdx.x;
  int bid = blockIdx.x;
  int bh = bid & 15, it = bid >> 4;       // 16 consecutive blocks share adj rows (L2)
  int b = bh >> 2, hh = bh & 3;
  int i0 = it * 64;
  int w8 = t >> 6, half = w8 >> 2, w = w8 & 3;
  int lane = t & 63, m = lane & 15, g = lane >> 4;

  {   // packed u/v for all 2048 j (u = 2^dstL, v = 2^(.2 dstL))
    const f32x4* dg = (const f32x4*)(dst + (size_t)bh * 2048);
    f32x4 dv = dg[t];
    u32x4 pk;
#pragma unroll
    for (int e = 0; e < 4; e++) {
      float uu = __builtin_amdgcn_exp2f(dv[e]);
      float vv = __builtin_amdgcn_exp2f(0.2f * dv[e]);
      unsigned rr_;
      asm("v_cvt_pk_bf16_f32 %0, %1, %2" : "=v"(rr_) : "v"(uu), "v"(vv));
      pk[e] = rr_;
    }
    ((u32x4*)uvl)[t] = pk;
  }

  int row_i = i0 + w * 16 + m;            // A-frag row this lane fills
  float srcL = src[(size_t)bh * 2048 + row_i];
  float Af = __builtin_amdgcn_exp2f(srcL);
  float Bf = __builtin_amdgcn_exp2f(LEAKY * srcL);

  s16x8 bones;
#pragma unroll
  for (int e = 0; e < 8; e++) bones[e] = (short)0x3F80;    // bf16 1.0

  f32x4 acc[4], accd;
#pragma unroll
  for (int db = 0; db < 4; db++) acc[db] = (f32x4){0.f, 0.f, 0.f, 0.f};
  accd = (f32x4){0.f, 0.f, 0.f, 0.f};

  char* wbase = (char*)whb4 + half * 16384;
  int ts = t & 255;
  int r_ = ts >> 2, ch_ = ts & 3;
  int jtbase = half * 16;
  const char* gbase = (const char*)(wht + (size_t)(bh * 64 + r_) * 2048) + jtbase * 128;
  int sw = (r_ & 7) << 4;
  u32x4 R0, R1;
  const u32x2* adjrow = (const u32x2*)(adjb + (size_t)row_i * 64 + jtbase * 2);

#define LOADT(jt_) { const u32x4* gp = (const u32x4*)(gbase + (jt_) * 128 + ch_ * 32); \
                     R0 = gp[0]; R1 = gp[1]; }
#define WRITET(pb_) { char* wb_ = (pb_); \
                      *(u32x4*)(wb_ + r_ * 128 + ((ch_ * 32) ^ sw)) = R0; \
                      *(u32x4*)(wb_ + r_ * 128 + ((ch_ * 32 + 16) ^ sw)) = R1; }

  LOADT(0); WRITET(wbase); LOADT(1);
  u32x2 adjw2 = adjrow[0];                // adjacency words for jt=0

  for (int jt = 0; jt < 16; jt++) {
    int cur = jt & 1;
    __syncthreads();                      // drains prefetch vmem + dbuf writes
    if (jt < 15) WRITET(wbase + (cur ^ 1) * 8192);   // tile jt+1 -> other buf
    if (jt < 14) LOADT(jt + 2);                      // issue tile jt+2 loads
    u32x2 adjnx;
    if (jt < 15) adjnx = adjrow[jt + 1];             // prefetch next adj words
    const char* wbufc = wbase + cur * 8192;
    int jglob = jtbase + jt;

#pragma unroll
    for (int ks = 0; ks < 2; ks++) {
      unsigned bits = (adjw2[ks] >> (g * 8)) & 0xffu;
      const u32x4* uvp = (const u32x4*)&uvl[jglob * 64 + ks * 32 + g * 8];
      u32x4 q0 = uvp[0], q1 = uvp[1];
      float pm[8];
#pragma unroll
      for (int e = 0; e < 8; e++) {
        unsigned pk = (e < 4) ? q0[e] : q1[e - 4];
        float uf = __builtin_bit_cast(float, pk << 16);
        float vf = __builtin_bit_cast(float, pk & 0xffff0000u);
        float p = fmaxf(Af * uf, Bf * vf);            // leaky-exp, factorized
        unsigned keep = (unsigned)(((int)(bits << (31 - e))) >> 31);
        pm[e] = __builtin_bit_cast(float, __builtin_bit_cast(unsigned, p) & keep);
      }
      u32x4 afu;
#pragma unroll
      for (int e2 = 0; e2 < 4; e2++) {
        unsigned rr_;
        asm("v_cvt_pk_bf16_f32 %0, %1, %2" : "=v"(rr_) : "v"(pm[2 * e2]), "v"(pm[2 * e2 + 1]));
        afu[e2] = rr_;
      }
      s16x8 af = __builtin_bit_cast(s16x8, afu);
#pragma unroll
      for (int db = 0; db < 4; db++) {
        int dl = db * 16 + m;
        int off = dl * 128 + ((ks * 64 + g * 16) ^ ((dl & 7) << 4));
        s16x8 bf = *(const s16x8*)(wbufc + off);
        acc[db] = __builtin_amdgcn_mfma_f32_16x16x32_bf16(af, bf, acc[db], 0, 0, 0);
      }
      accd = __builtin_amdgcn_mfma_f32_16x16x32_bf16(af, bones, accd, 0, 0, 0);
    }
    adjw2 = adjnx;
  }
#undef LOADT
#undef WRITET

  __syncthreads();                        // whb4 dead; reuse as combine buffer
  float* accl = (float*)whb4;             // [row][65] (col 64 = den)
  if (half == 1) {
#pragma unroll
    for (int db = 0; db < 4; db++)
#pragma unroll
      for (int r = 0; r < 4; r++)
        accl[(w * 16 + 4 * g + r) * 65 + db * 16 + m] = acc[db][r];
    if (m == 0) {
#pragma unroll
      for (int r = 0; r < 4; r++)
        accl[(w * 16 + 4 * g + r) * 65 + 64] = accd[r];
    }
  }
  __syncthreads();

  if (half == 0) {
#pragma unroll
    for (int db = 0; db < 4; db++)
#pragma unroll
      for (int r = 0; r < 4; r++)
        acc[db][r] += accl[(w * 16 + 4 * g + r) * 65 + db * 16 + m];
    float inv[4];
#pragma unroll
    for (int r = 0; r < 4; r++) {
      float dtot = accd[r] + accl[(w * 16 + 4 * g + r) * 65 + 64];
      inv[r] = dtot > 0.f ? 1.0f / dtot : 0.f;  // all-masked row -> zeros
    }

    float sums[4] = {0.f, 0.f, 0.f, 0.f}, sqs[4] = {0.f, 0.f, 0.f, 0.f};
#pragma unroll
    for (int r = 0; r < 4; r++) {
      int n = i0 + w * 16 + 4 * g + r;
#pragma unroll
      for (int db = 0; db < 4; db++) {
        float val = acc[db][r] * inv[r];
        hnew[(size_t)(b * 2048 + n) * 256 + hh * 64 + db * 16 + m] = val;
        sums[db] += val;
        sqs[db] += val * val;
      }
    }
#pragma unroll
    for (int db = 0; db < 4; db++) {
      sums[db] += __shfl_xor(sums[db], 16); sums[db] += __shfl_xor(sums[db], 32);
      sqs[db]  += __shfl_xor(sqs[db], 16);  sqs[db]  += __shfl_xor(sqs[db], 32);
    }
    if (g == 0) {
#pragma unroll
      for (int db = 0; db < 4; db++) {
        redS[w * 64 + db * 16 + m] = sums[db];
        redQ[w * 64 + db * 16 + m] = sqs[db];
      }
    }
  }
  __syncthreads();
  if (t < 64) {
    float ts2 = redS[t] + redS[64 + t] + redS[128 + t] + redS[192 + t];
    float tq = redQ[t] + redQ[64 + t] + redQ[128 + t] + redQ[192 + t];
    atomicAdd(&chsum[hh * 64 + t], ts2);
    atomicAdd(&chsq[hh * 64 + t], tq);
  }
}

// ---------------- Kernel D: BN(+stats inline) + ELU -----------------------
__global__ __launch_bounds__(256) void k_bn_elu(const float* __restrict__ hnew,
                                                const float* __restrict__ chsum,
                                                const float* __restrict__ chsq,
                                                const float* __restrict__ gamma,
                                                const float* __restrict__ beta,
                                                float* __restrict__ out) {
  int idx4 = blockIdx.x * 256 + threadIdx.x;
  f32x4 x = ((const f32x4*)hnew)[idx4];
  int c0 = (idx4 * 4) & 255;
  f32x4 s = *(const f32x4*)(chsum + c0);
  f32x4 sq = *(const f32x4*)(chsq + c0);
  f32x4 gm = *(const f32x4*)(gamma + c0);
  f32x4 bt = *(const f32x4*)(beta + c0);
  f32x4 y;
#pragma unroll
  for (int e = 0; e < 4; e++) {
    float mean = s[e] * (1.0f / 8192.0f);
    float var = sq[e] * (1.0f / 8192.0f) - mean * mean;
    float sc = gm[e] * rsqrtf(var + BNEPS);
    float v = (x[e] - mean) * sc + bt[e];
    y[e] = v > 0.f ? v : expm1f(v);
  }
  ((f32x4*)out)[idx4] = y;
}

extern "C" void kernel_launch(void* const* d_in, const int* in_sizes, int n_in,
                              void* d_out, int out_size, void* d_ws, size_t ws_size,
                              hipStream_t stream) {
  const float* h = (const float*)d_in[0];
  const float* W = (const float*)d_in[1];
  const float* a = (const float*)d_in[2];
  const float* gamma = (const float*)d_in[3];
  const float* beta = (const float*)d_in[4];
  const int* adj = (const int*)d_in[5];

  char* ws = (char*)d_ws;
  unsigned* adjb = (unsigned*)ws;                                  // 512 KB
  unsigned short* wht = (unsigned short*)(ws + (512 << 10));       // 4 MB
  float* src = (float*)(ws + (512 << 10) + (4 << 20));             // 128 KB
  float* dst = src + 16 * 2048;                                    // 128 KB
  float* chsum = dst + 16 * 2048;                                  // 256
  float* chsq = chsum + 256;                                       // 256
  float* hnew = (float*)(ws + (512 << 10) + (5 << 20));            // 8 MB

  k_pre<<<512 + (N_ * N_) / 256, 256, 0, stream>>>(adj, W, h, a, adjb, chsum,
                                                   wht, src, dst);
  k_attn<<<B_ * H_ * (N_ / 64), 512, 0, stream>>>(adjb, wht, src, dst,
                                                  hnew, chsum, chsq);
  k_bn_elu<<<(B_ * N_ * HD_) / 1024, 256, 0, stream>>>(hnew, chsum, chsq,
                                                       gamma, beta, (float*)d_out);
}